// Round 10
// baseline (168.324 us; speedup 1.0000x reference)
//
#include <hip/hip_runtime.h>

// Swin shifted-window MHSA, fused per-window kernel, v9.
// 1 block = 1 window (S=64, C=128), 256 threads = 4 waves, wave h = head h.
// v5 numerics (normalize-before-pack: proven 4.9e-4) with:
//  - fused single-pass Q/K/V projection (v2 shape: one xf read feeds 6 MFMAs)
//  - 16KB LDS, staging aliased onto Xw (v2-proven), 3 barriers
//  - s_setprio around MFMA clusters (T5)
// NO __launch_bounds__ min-wave cap (v6:85 / v7:102 caps -> NaN codegen).
// Unnormalized-exp refold is banned (v8: 10x precision loss).

typedef __attribute__((ext_vector_type(8))) short bf16x8;   // 8 bf16 = 4 VGPR
typedef __attribute__((ext_vector_type(4))) float f32x4;    // MFMA C/D

#define MFMA16(a, b, c) __builtin_amdgcn_mfma_f32_16x16x32_bf16((a), (b), (c), 0, 0, 0)
#define EXP2F(x) __builtin_amdgcn_exp2f(x)
#define PRIO1() __builtin_amdgcn_s_setprio(1)
#define PRIO0() __builtin_amdgcn_s_setprio(0)

#define LDS_BYTES 16384   // Xw [64][128] bf16 swizzled; later attn-out staging (aliased)

__device__ __forceinline__ unsigned int cvt_pk(float lo, float hi) {
  unsigned int r;
  asm("v_cvt_pk_bf16_f32 %0, %1, %2" : "=v"(r) : "v"(lo), "v"(hi));
  return r;
}
__device__ __forceinline__ unsigned short f2bf1(float f) {
  return (unsigned short)(cvt_pk(f, f) & 0xffffu);
}
__device__ __forceinline__ bf16x8 pack8(f32x4 a, f32x4 b) {
  union { unsigned int w[4]; bf16x8 v; } u;
  u.w[0] = cvt_pk(a[0], a[1]); u.w[1] = cvt_pk(a[2], a[3]);
  u.w[2] = cvt_pk(b[0], b[1]); u.w[3] = cvt_pk(b[2], b[3]);
  return u.v;
}
__device__ __forceinline__ bf16x8 packf4(float4 lo, float4 hi) {
  union { unsigned int w[4]; bf16x8 v; } u;
  u.w[0] = cvt_pk(lo.x, lo.y); u.w[1] = cvt_pk(lo.z, lo.w);
  u.w[2] = cvt_pk(hi.x, hi.y); u.w[3] = cvt_pk(hi.z, hi.w);
  return u.v;
}

// prep: transpose weights to bf16 Wt[n][k] (q,k,v,o) + expand rel-pos bias to
// [4][64][64] f32 in exp2 domain, with the (window-invariant) shift mask baked in.
__global__ void prep_kernel(const float* __restrict__ wq, const float* __restrict__ wk,
                            const float* __restrict__ wv, const float* __restrict__ wo,
                            const float* __restrict__ bias_table,
                            const int* __restrict__ shiftp,
                            unsigned short* __restrict__ wt, float* __restrict__ bias_full) {
  int tid = blockIdx.x * 256 + threadIdx.x;            // 65536 threads
  int m = tid >> 14, idx = tid & 16383;
  int n = idx >> 7, k = idx & 127;
  const float* w = (m == 0) ? wq : (m == 1) ? wk : (m == 2) ? wv : wo;
  wt[m * 16384 + n * 128 + k] = f2bf1(w[k * 128 + n]);
  if (tid < 16384) {                                    // bias_full[h][s1][s2]
    int h = tid >> 12, r = tid & 4095;
    int s1 = r >> 6, s2 = r & 63;
    int rel = ((s1 >> 3) - (s2 >> 3) + 7) * 15 + ((s1 & 7) - (s2 & 7) + 7);
    float v = bias_table[rel * 4 + h];
    // shifted-window mask: partition by (row>=4, col>=4) within the window --
    // identical for every window when H,W are multiples of WS and roll wraps.
    if (shiftp[0]) {
      int same = (((s1 >> 3) >= 4) == ((s2 >> 3) >= 4)) &
                 (((s1 & 7) >= 4) == ((s2 & 7) >= 4));
      if (!same) v -= 100.0f;
    }
    bias_full[tid] = v * 1.4426950408889634f;           // * log2(e)
  }
}

__global__ __launch_bounds__(256) void winattn_kernel(
    const float* __restrict__ x,
    const float* __restrict__ bq, const float* __restrict__ bk,
    const float* __restrict__ bv, const float* __restrict__ bo,
    const unsigned short* __restrict__ wt,
    const float* __restrict__ bias_full,
    const int* __restrict__ shiftp,
    float* __restrict__ out) {
  __shared__ __align__(16) char smem[LDS_BYTES];
  const int tid = threadIdx.x;
  const int h = tid >> 6, lane = tid & 63;
  const int g = lane >> 4, c16 = lane & 15;
  const int win = blockIdx.x;
  const int bb = win >> 8, wh = (win >> 4) & 15, ww = win & 15;
  const int ss = shiftp[0] ? 4 : 0;
  const f32x4 z4 = {0.f, 0.f, 0.f, 0.f};

  // ---- Phase A: gather shifted window tokens -> Xw (bf16, swizzled) ----
#pragma unroll
  for (int it = 0; it < 4; ++it) {
    int cid = tid + it * 256;                 // 1024 chunks of 8 channels
    int s = cid >> 4, cc = (cid & 15) << 3;
    int r0 = (wh * 8 + (s >> 3) + ss) & 127;  // roll(-ss): src = pos + ss (mod 128)
    int c0 = (ww * 8 + (s & 7) + ss) & 127;
    const float* src = x + ((bb * 16384 + r0 * 128 + c0) * 128 + cc);
    float4 lo = *(const float4*)src;
    float4 hi = *(const float4*)(src + 4);
    *(bf16x8*)(smem + s * 256 + ((cc * 2) ^ ((s & 7) << 4))) = packf4(lo, hi);
  }
  __syncthreads();

  // ---- Phase B: fused Q^T / K^T / V projections (one xf read -> 6 MFMAs) ----
  f32x4 qacc[2][4], kacc[2][4], vacc[4][2];
#pragma unroll
  for (int i = 0; i < 4; ++i) {
    qacc[0][i] = z4; qacc[1][i] = z4;
    kacc[0][i] = z4; kacc[1][i] = z4;
    vacc[i][0] = z4; vacc[i][1] = z4;
  }
  const unsigned short* wq_ = wt + (h * 32 + c16) * 128;
  const unsigned short* wk_ = wt + 16384 + (h * 32 + c16) * 128;
  const unsigned short* wv_ = wt + 32768 + (h * 32 + c16) * 128;
  PRIO1();
#pragma unroll
  for (int kk = 0; kk < 4; ++kk) {
    const int co = kk * 32 + g * 8;
    bf16x8 xfr[4];
#pragma unroll
    for (int t = 0; t < 4; ++t) {
      int row = t * 16 + c16;
      xfr[t] = *(const bf16x8*)(smem + row * 256 + ((co * 2) ^ ((row & 7) << 4)));
    }
    bf16x8 wqf0 = *(const bf16x8*)(wq_ + co);
    bf16x8 wqf1 = *(const bf16x8*)(wq_ + 2048 + co);
    bf16x8 wkf0 = *(const bf16x8*)(wk_ + co);
    bf16x8 wkf1 = *(const bf16x8*)(wk_ + 2048 + co);
    bf16x8 wvf0 = *(const bf16x8*)(wv_ + co);
    bf16x8 wvf1 = *(const bf16x8*)(wv_ + 2048 + co);
#pragma unroll
    for (int t = 0; t < 4; ++t) {
      qacc[0][t] = MFMA16(wqf0, xfr[t], qacc[0][t]);
      qacc[1][t] = MFMA16(wqf1, xfr[t], qacc[1][t]);
      kacc[0][t] = MFMA16(wkf0, xfr[t], kacc[0][t]);
      kacc[1][t] = MFMA16(wkf1, xfr[t], kacc[1][t]);
      vacc[t][0] = MFMA16(xfr[t], wvf0, vacc[t][0]);
      vacc[t][1] = MFMA16(xfr[t], wvf1, vacc[t][1]);
    }
  }
  PRIO0();
  __syncthreads();   // all waves done reading Xw; smem becomes attn-out staging

  // bias (+ exp2-domain scale folded into Q), pack with k-mapping pi(g,j)=(j>>2)*16+g*4+(j&3)
  bf16x8 qb16[4], kb16[4], vb16[2][2];
  {
    const float scale = 0.17677669529663687f * 1.4426950408889634f;  // 1/sqrt(32)*log2e
    f32x4 bq4[2], bk4[2];
    bq4[0] = *(const f32x4*)(bq + h * 32 + g * 4);
    bq4[1] = *(const f32x4*)(bq + h * 32 + 16 + g * 4);
    bk4[0] = *(const f32x4*)(bk + h * 32 + g * 4);
    bk4[1] = *(const f32x4*)(bk + h * 32 + 16 + g * 4);
#pragma unroll
    for (int t = 0; t < 4; ++t) {
      f32x4 q0, q1, k0, k1;
#pragma unroll
      for (int r = 0; r < 4; ++r) {
        q0[r] = (qacc[0][t][r] + bq4[0][r]) * scale;
        q1[r] = (qacc[1][t][r] + bq4[1][r]) * scale;
        k0[r] = kacc[0][t][r] + bk4[0][r];
        k1[r] = kacc[1][t][r] + bk4[1][r];
      }
      qb16[t] = pack8(q0, q1);
      kb16[t] = pack8(k0, k1);
    }
    float bv0 = bv[h * 32 + c16];
    float bv1 = bv[h * 32 + 16 + c16];
#pragma unroll
    for (int ks = 0; ks < 2; ++ks) {
      f32x4 v00, v10, v01, v11;
#pragma unroll
      for (int r = 0; r < 4; ++r) {
        v00[r] = vacc[2 * ks][0][r] + bv0;
        v10[r] = vacc[2 * ks + 1][0][r] + bv0;
        v01[r] = vacc[2 * ks][1][r] + bv1;
        v11[r] = vacc[2 * ks + 1][1][r] + bv1;
      }
      vb16[ks][0] = pack8(v00, v10);
      vb16[ks][1] = pack8(v01, v11);
    }
  }

  // ---- Phases C/D streamed per s1-chunk: QK -> softmax -> PV -> stage ----
  const float* bfh = bias_full + h * 4096 + c16 * 64 + g * 4;
#pragma unroll
  for (int b = 0; b < 4; ++b) {
    PRIO1();
    f32x4 s0 = MFMA16(kb16[0], qb16[b], z4);
    f32x4 s1 = MFMA16(kb16[1], qb16[b], z4);
    f32x4 s2 = MFMA16(kb16[2], qb16[b], z4);
    f32x4 s3 = MFMA16(kb16[3], qb16[b], z4);
    PRIO0();
    const float* bfr = bfh + b * 1024;
    f32x4 bia0 = *(const f32x4*)(bfr);
    f32x4 bia1 = *(const f32x4*)(bfr + 16);
    f32x4 bia2 = *(const f32x4*)(bfr + 32);
    f32x4 bia3 = *(const f32x4*)(bfr + 48);
#pragma unroll
    for (int r = 0; r < 4; ++r) {
      s0[r] += bia0[r]; s1[r] += bia1[r]; s2[r] += bia2[r]; s3[r] += bia3[r];
    }
    f32x4 m01, m23;
#pragma unroll
    for (int r = 0; r < 4; ++r) {
      m01[r] = fmaxf(s0[r], s1[r]);
      m23[r] = fmaxf(s2[r], s3[r]);
    }
    float mx = fmaxf(fmaxf(fmaxf(m01[0], m01[1]), fmaxf(m01[2], m01[3])),
                     fmaxf(fmaxf(m23[0], m23[1]), fmaxf(m23[2], m23[3])));
    mx = fmaxf(mx, __shfl_xor(mx, 16));
    mx = fmaxf(mx, __shfl_xor(mx, 32));
#pragma unroll
    for (int r = 0; r < 4; ++r) {
      s0[r] = EXP2F(s0[r] - mx); s1[r] = EXP2F(s1[r] - mx);
      s2[r] = EXP2F(s2[r] - mx); s3[r] = EXP2F(s3[r] - mx);
    }
    f32x4 t01, t23;
#pragma unroll
    for (int r = 0; r < 4; ++r) {
      t01[r] = s0[r] + s1[r];
      t23[r] = s2[r] + s3[r];
    }
    float sum = ((t01[0] + t01[1]) + (t01[2] + t01[3])) +
                ((t23[0] + t23[1]) + (t23[2] + t23[3]));
    sum += __shfl_xor(sum, 16);
    sum += __shfl_xor(sum, 32);
    float inv = 1.0f / sum;
#pragma unroll
    for (int r = 0; r < 4; ++r) {
      s0[r] *= inv; s1[r] *= inv; s2[r] *= inv; s3[r] *= inv;
    }
    bf16x8 pa0 = pack8(s0, s1);
    bf16x8 pa1 = pack8(s2, s3);

    PRIO1();
    f32x4 o0 = MFMA16(pa0, vb16[0][0], z4);
    f32x4 o1 = MFMA16(pa0, vb16[0][1], z4);
    o0 = MFMA16(pa1, vb16[1][0], o0);
    o1 = MFMA16(pa1, vb16[1][1], o1);
    PRIO0();

    // stage attn-out rows for this chunk (aliased onto Xw; reads done pre-barrier)
#pragma unroll
    for (int r = 0; r < 4; ++r) {
      int row = b * 16 + g * 4 + r;
      int sw = (row & 7) << 4;
      int col0 = h * 32 + c16;
      *(unsigned short*)(smem + row * 256 + ((col0 * 2) ^ sw)) = f2bf1(o0[r]);
      *(unsigned short*)(smem + row * 256 + (((col0 + 16) * 2) ^ sw)) = f2bf1(o1[r]);
    }
  }
  __syncthreads();   // staging complete across waves

  // ---- Phase F: output projection -> global fp32 ----
  {
    f32x4 acc[8];
#pragma unroll
    for (int nt = 0; nt < 8; ++nt) acc[nt] = z4;
    const int arow = h * 16 + c16;
    const int asw = (arow & 7) << 4;
    PRIO1();
#pragma unroll
    for (int kk = 0; kk < 4; ++kk) {
      const int co = kk * 32 + g * 8;
      bf16x8 a = *(const bf16x8*)(smem + arow * 256 + ((co * 2) ^ asw));
#pragma unroll
      for (int nt = 0; nt < 8; ++nt) {
        bf16x8 bfr = *(const bf16x8*)(wt + 49152 + (nt * 16 + c16) * 128 + co);
        acc[nt] = MFMA16(a, bfr, acc[nt]);
      }
    }
    PRIO0();
#pragma unroll
    for (int nt = 0; nt < 8; ++nt) {
      int n = nt * 16 + c16;
      float bn = bo[n];
#pragma unroll
      for (int r = 0; r < 4; ++r) {
        int row = h * 16 + g * 4 + r;
        out[(size_t)win * 8192 + (size_t)(row * 128 + n)] = acc[nt][r] + bn;
      }
    }
  }
}

extern "C" void kernel_launch(void* const* d_in, const int* in_sizes, int n_in,
                              void* d_out, int out_size, void* d_ws, size_t ws_size,
                              hipStream_t stream) {
  const float* x = (const float*)d_in[0];
  const float* wq = (const float*)d_in[1];
  const float* bq = (const float*)d_in[2];
  const float* wk = (const float*)d_in[3];
  const float* bk = (const float*)d_in[4];
  const float* wv = (const float*)d_in[5];
  const float* bv = (const float*)d_in[6];
  const float* wo = (const float*)d_in[7];
  const float* bo = (const float*)d_in[8];
  const float* bias_table = (const float*)d_in[9];
  const int* shiftp = (const int*)d_in[10];

  unsigned short* wt = (unsigned short*)d_ws;                    // 4*128*128 bf16 = 128KB
  float* bias_full = (float*)((char*)d_ws + 131072);             // 4*64*64 f32 = 64KB

  prep_kernel<<<256, 256, 0, stream>>>(wq, wk, wv, wo, bias_table, shiftp, wt, bias_full);
  winattn_kernel<<<4096, 256, 0, stream>>>(x, bq, bk, bv, bo, wt, bias_full, shiftp,
                                           (float*)d_out);
}

// Round 11
// 167.512 us; speedup vs baseline: 1.0048x; 1.0048x over previous
//
#include <hip/hip_runtime.h>

// Swin shifted-window MHSA, fused per-window kernel, v11.
// = v5 (proven best, 161.7us) with zero-cost algebraic folds:
//  - bias folded into MFMA accumulator init (K/V/Q proj, QK scores, out-proj)
//  - Wq prescaled by (1/sqrt(dk))*log2(e) at prep (Q pack has no muls)
//  - no max-subtraction in softmax (scores are exp2-domain tiny; mask -> exp2~0)
// 1 block = 1 window (S=64, C=128), 256 threads = 4 waves, wave h = head h.
// 3-pass QKV projection; streamed score chunks; shift mask baked into bias_full;
// exp2 softmax; cvt_pk packing; normalize-before-pack (v8 refold banned);
// NO forced __launch_bounds__ cap (v6/v7 NaN); no setprio (clean attribution).

typedef __attribute__((ext_vector_type(8))) short bf16x8;   // 8 bf16 = 4 VGPR
typedef __attribute__((ext_vector_type(4))) float f32x4;    // MFMA C/D

#define MFMA16(a, b, c) __builtin_amdgcn_mfma_f32_16x16x32_bf16((a), (b), (c), 0, 0, 0)
#define EXP2F(x) __builtin_amdgcn_exp2f(x)

#define XW_OFF 0         // 16KB: Xw [64][128] bf16, row-XOR swizzled
#define STG_OFF 16384    // 16KB: attn-out staging [64][128] bf16, swizzled
#define LDS_BYTES 32768

__device__ __forceinline__ unsigned int cvt_pk(float lo, float hi) {
  unsigned int r;
  asm("v_cvt_pk_bf16_f32 %0, %1, %2" : "=v"(r) : "v"(lo), "v"(hi));
  return r;
}
__device__ __forceinline__ unsigned short f2bf1(float f) {
  return (unsigned short)(cvt_pk(f, f) & 0xffffu);
}
__device__ __forceinline__ bf16x8 pack8(f32x4 a, f32x4 b) {
  union { unsigned int w[4]; bf16x8 v; } u;
  u.w[0] = cvt_pk(a[0], a[1]); u.w[1] = cvt_pk(a[2], a[3]);
  u.w[2] = cvt_pk(b[0], b[1]); u.w[3] = cvt_pk(b[2], b[3]);
  return u.v;
}
__device__ __forceinline__ bf16x8 packf4(float4 lo, float4 hi) {
  union { unsigned int w[4]; bf16x8 v; } u;
  u.w[0] = cvt_pk(lo.x, lo.y); u.w[1] = cvt_pk(lo.z, lo.w);
  u.w[2] = cvt_pk(hi.x, hi.y); u.w[3] = cvt_pk(hi.z, hi.w);
  return u.v;
}

// prep: transpose weights to bf16 Wt[n][k] (q prescaled, k, v, o) + expand
// rel-pos bias to [4][64][64] f32 in exp2 domain with shift mask baked in.
__global__ void prep_kernel(const float* __restrict__ wq, const float* __restrict__ wk,
                            const float* __restrict__ wv, const float* __restrict__ wo,
                            const float* __restrict__ bias_table,
                            const int* __restrict__ shiftp,
                            unsigned short* __restrict__ wt, float* __restrict__ bias_full) {
  const float QS = 0.17677669529663687f * 1.4426950408889634f;  // 1/sqrt(32)*log2e
  int tid = blockIdx.x * 256 + threadIdx.x;            // 65536 threads
  int m = tid >> 14, idx = tid & 16383;
  int n = idx >> 7, k = idx & 127;
  const float* w = (m == 0) ? wq : (m == 1) ? wk : (m == 2) ? wv : wo;
  float wval = w[k * 128 + n];
  if (m == 0) wval *= QS;                               // prescale Wq
  wt[m * 16384 + n * 128 + k] = f2bf1(wval);
  if (tid < 16384) {                                    // bias_full[h][s1][s2]
    int h = tid >> 12, r = tid & 4095;
    int s1 = r >> 6, s2 = r & 63;
    int rel = ((s1 >> 3) - (s2 >> 3) + 7) * 15 + ((s1 & 7) - (s2 & 7) + 7);
    float v = bias_table[rel * 4 + h];
    // shifted-window mask: partition by (row>=4, col>=4) within the window --
    // identical for every window when H,W are multiples of WS and roll wraps.
    if (shiftp[0]) {
      int same = (((s1 >> 3) >= 4) == ((s2 >> 3) >= 4)) &
                 (((s1 & 7) >= 4) == ((s2 & 7) >= 4));
      if (!same) v -= 100.0f;
    }
    bias_full[tid] = v * 1.4426950408889634f;           // * log2(e)
  }
}

__global__ __launch_bounds__(256) void winattn_kernel(
    const float* __restrict__ x,
    const float* __restrict__ bq, const float* __restrict__ bk,
    const float* __restrict__ bv, const float* __restrict__ bo,
    const unsigned short* __restrict__ wt,
    const float* __restrict__ bias_full,
    const int* __restrict__ shiftp,
    float* __restrict__ out) {
  __shared__ __align__(16) char smem[LDS_BYTES];
  const int tid = threadIdx.x;
  const int h = tid >> 6, lane = tid & 63;
  const int g = lane >> 4, c16 = lane & 15;
  const int win = blockIdx.x;
  const int bb = win >> 8, wh = (win >> 4) & 15, ww = win & 15;
  const int ss = shiftp[0] ? 4 : 0;

  // ---- Phase A: gather shifted window tokens -> Xw (bf16, swizzled) ----
#pragma unroll
  for (int it = 0; it < 4; ++it) {
    int cid = tid + it * 256;                 // 1024 chunks of 8 channels
    int s = cid >> 4, cc = (cid & 15) << 3;
    int r0 = (wh * 8 + (s >> 3) + ss) & 127;  // roll(-ss): src = pos + ss (mod 128)
    int c0 = (ww * 8 + (s & 7) + ss) & 127;
    const float* src = x + ((bb * 16384 + r0 * 128 + c0) * 128 + cc);
    float4 lo = *(const float4*)src;
    float4 hi = *(const float4*)(src + 4);
    *(bf16x8*)(smem + XW_OFF + s * 256 + ((cc * 2) ^ ((s & 7) << 4))) = packf4(lo, hi);
  }
  __syncthreads();

  // ---- Phase B: three passes (K, V, Q); bias pre-loaded into accumulators ----
  bf16x8 qb16[4], kb16[4], vb16[2][2];
  const unsigned short* wq_ = wt + (h * 32 + c16) * 128;
  const unsigned short* wk_ = wt + 16384 + (h * 32 + c16) * 128;
  const unsigned short* wv_ = wt + 32768 + (h * 32 + c16) * 128;

  {  // pass K: K^T[ch][s2] = Wk rows x Xw^T + bk (in acc init)
    f32x4 b0 = *(const f32x4*)(bk + h * 32 + g * 4);
    f32x4 b1 = *(const f32x4*)(bk + h * 32 + 16 + g * 4);
    f32x4 a0[4], a1[4];
#pragma unroll
    for (int t = 0; t < 4; ++t) { a0[t] = b0; a1[t] = b1; }
#pragma unroll
    for (int kk = 0; kk < 4; ++kk) {
      const int co = kk * 32 + g * 8;
      bf16x8 wf0 = *(const bf16x8*)(wk_ + co);
      bf16x8 wf1 = *(const bf16x8*)(wk_ + 2048 + co);
#pragma unroll
      for (int t = 0; t < 4; ++t) {
        int row = t * 16 + c16;
        bf16x8 xf = *(const bf16x8*)(smem + XW_OFF + row * 256 + ((co * 2) ^ ((row & 7) << 4)));
        a0[t] = MFMA16(wf0, xf, a0[t]);
        a1[t] = MFMA16(wf1, xf, a1[t]);
      }
    }
#pragma unroll
    for (int t = 0; t < 4; ++t) kb16[t] = pack8(a0[t], a1[t]);
  }

  {  // pass V: V[s2][d] = Xw x Wv + bv (in acc init)
    float bv0 = bv[h * 32 + c16];
    float bv1 = bv[h * 32 + 16 + c16];
    f32x4 i0 = {bv0, bv0, bv0, bv0};
    f32x4 i1 = {bv1, bv1, bv1, bv1};
    f32x4 a0[4], a1[4];
#pragma unroll
    for (int t = 0; t < 4; ++t) { a0[t] = i0; a1[t] = i1; }
#pragma unroll
    for (int kk = 0; kk < 4; ++kk) {
      const int co = kk * 32 + g * 8;
      bf16x8 wf0 = *(const bf16x8*)(wv_ + co);
      bf16x8 wf1 = *(const bf16x8*)(wv_ + 2048 + co);
#pragma unroll
      for (int t = 0; t < 4; ++t) {
        int row = t * 16 + c16;
        bf16x8 xf = *(const bf16x8*)(smem + XW_OFF + row * 256 + ((co * 2) ^ ((row & 7) << 4)));
        a0[t] = MFMA16(xf, wf0, a0[t]);
        a1[t] = MFMA16(xf, wf1, a1[t]);
      }
    }
#pragma unroll
    for (int ks = 0; ks < 2; ++ks) {
      vb16[ks][0] = pack8(a0[2 * ks], a0[2 * ks + 1]);
      vb16[ks][1] = pack8(a1[2 * ks], a1[2 * ks + 1]);
    }
  }

  {  // pass Q: Q^T[ch][s1]; Wq prescaled at prep; bq*QS in acc init
    const float QS = 0.17677669529663687f * 1.4426950408889634f;
    f32x4 b0 = *(const f32x4*)(bq + h * 32 + g * 4);
    f32x4 b1 = *(const f32x4*)(bq + h * 32 + 16 + g * 4);
    f32x4 i0, i1;
#pragma unroll
    for (int r = 0; r < 4; ++r) { i0[r] = b0[r] * QS; i1[r] = b1[r] * QS; }
    f32x4 a0[4], a1[4];
#pragma unroll
    for (int t = 0; t < 4; ++t) { a0[t] = i0; a1[t] = i1; }
#pragma unroll
    for (int kk = 0; kk < 4; ++kk) {
      const int co = kk * 32 + g * 8;
      bf16x8 wf0 = *(const bf16x8*)(wq_ + co);
      bf16x8 wf1 = *(const bf16x8*)(wq_ + 2048 + co);
#pragma unroll
      for (int t = 0; t < 4; ++t) {
        int row = t * 16 + c16;
        bf16x8 xf = *(const bf16x8*)(smem + XW_OFF + row * 256 + ((co * 2) ^ ((row & 7) << 4)));
        a0[t] = MFMA16(wf0, xf, a0[t]);
        a1[t] = MFMA16(wf1, xf, a1[t]);
      }
    }
#pragma unroll
    for (int t = 0; t < 4; ++t) qb16[t] = pack8(a0[t], a1[t]);
  }

  // ---- Phases C/D streamed per s1-chunk: QK(+bias in acc) -> exp2 -> PV -> stage ----
  // No max-subtraction: exp2-domain scores are O(1); masked scores ~-144 -> exp2 ~ 0.
  const float* bfh = bias_full + h * 4096 + c16 * 64 + g * 4;
#pragma unroll
  for (int b = 0; b < 4; ++b) {
    const float* bfr = bfh + b * 1024;
    f32x4 bia0 = *(const f32x4*)(bfr);
    f32x4 bia1 = *(const f32x4*)(bfr + 16);
    f32x4 bia2 = *(const f32x4*)(bfr + 32);
    f32x4 bia3 = *(const f32x4*)(bfr + 48);
    f32x4 s0 = MFMA16(kb16[0], qb16[b], bia0);
    f32x4 s1 = MFMA16(kb16[1], qb16[b], bia1);
    f32x4 s2 = MFMA16(kb16[2], qb16[b], bia2);
    f32x4 s3 = MFMA16(kb16[3], qb16[b], bia3);
#pragma unroll
    for (int r = 0; r < 4; ++r) {
      s0[r] = EXP2F(s0[r]); s1[r] = EXP2F(s1[r]);
      s2[r] = EXP2F(s2[r]); s3[r] = EXP2F(s3[r]);
    }
    f32x4 t01, t23;
#pragma unroll
    for (int r = 0; r < 4; ++r) {
      t01[r] = s0[r] + s1[r];
      t23[r] = s2[r] + s3[r];
    }
    float sum = ((t01[0] + t01[1]) + (t01[2] + t01[3])) +
                ((t23[0] + t23[1]) + (t23[2] + t23[3]));
    sum += __shfl_xor(sum, 16);
    sum += __shfl_xor(sum, 32);
    float inv = 1.0f / sum;
#pragma unroll
    for (int r = 0; r < 4; ++r) {
      s0[r] *= inv; s1[r] *= inv; s2[r] *= inv; s3[r] *= inv;
    }
    bf16x8 pa0 = pack8(s0, s1);
    bf16x8 pa1 = pack8(s2, s3);

    f32x4 z4 = {0.f, 0.f, 0.f, 0.f};
    f32x4 o0 = MFMA16(pa0, vb16[0][0], z4);
    f32x4 o1 = MFMA16(pa0, vb16[0][1], z4);
    o0 = MFMA16(pa1, vb16[1][0], o0);
    o1 = MFMA16(pa1, vb16[1][1], o1);

    // stage attn-out rows for this chunk (own region; barrier after loop)
#pragma unroll
    for (int r = 0; r < 4; ++r) {
      int row = b * 16 + g * 4 + r;
      int sw = (row & 7) << 4;
      int col0 = h * 32 + c16;
      *(unsigned short*)(smem + STG_OFF + row * 256 + ((col0 * 2) ^ sw)) = f2bf1(o0[r]);
      *(unsigned short*)(smem + STG_OFF + row * 256 + (((col0 + 16) * 2) ^ sw)) = f2bf1(o1[r]);
    }
  }
  __syncthreads();   // STG complete across waves

  // ---- Phase F: output projection -> global fp32 (bo in acc init) ----
  {
    f32x4 acc[8];
#pragma unroll
    for (int nt = 0; nt < 8; ++nt) {
      float bn = bo[nt * 16 + c16];
      acc[nt][0] = bn; acc[nt][1] = bn; acc[nt][2] = bn; acc[nt][3] = bn;
    }
    const int arow = h * 16 + c16;
    const int asw = (arow & 7) << 4;
#pragma unroll
    for (int kk = 0; kk < 4; ++kk) {
      const int co = kk * 32 + g * 8;
      bf16x8 a = *(const bf16x8*)(smem + STG_OFF + arow * 256 + ((co * 2) ^ asw));
#pragma unroll
      for (int nt = 0; nt < 8; ++nt) {
        bf16x8 bfr = *(const bf16x8*)(wt + 49152 + (nt * 16 + c16) * 128 + co);
        acc[nt] = MFMA16(a, bfr, acc[nt]);
      }
    }
#pragma unroll
    for (int nt = 0; nt < 8; ++nt) {
      int n = nt * 16 + c16;
#pragma unroll
      for (int r = 0; r < 4; ++r) {
        int row = h * 16 + g * 4 + r;
        out[(size_t)win * 8192 + (size_t)(row * 128 + n)] = acc[nt][r];
      }
    }
  }
}

extern "C" void kernel_launch(void* const* d_in, const int* in_sizes, int n_in,
                              void* d_out, int out_size, void* d_ws, size_t ws_size,
                              hipStream_t stream) {
  const float* x = (const float*)d_in[0];
  const float* wq = (const float*)d_in[1];
  const float* bq = (const float*)d_in[2];
  const float* wk = (const float*)d_in[3];
  const float* bk = (const float*)d_in[4];
  const float* wv = (const float*)d_in[5];
  const float* bv = (const float*)d_in[6];
  const float* wo = (const float*)d_in[7];
  const float* bo = (const float*)d_in[8];
  const float* bias_table = (const float*)d_in[9];
  const int* shiftp = (const int*)d_in[10];

  unsigned short* wt = (unsigned short*)d_ws;                    // 4*128*128 bf16 = 128KB
  float* bias_full = (float*)((char*)d_ws + 131072);             // 4*64*64 f32 = 64KB

  prep_kernel<<<256, 256, 0, stream>>>(wq, wk, wv, wo, bias_table, shiftp, wt, bias_full);
  winattn_kernel<<<4096, 256, 0, stream>>>(x, bq, bk, bv, bo, wt, bias_full, shiftp,
                                           (float*)d_out);
}